// Round 2
// baseline (238.980 us; speedup 1.0000x reference)
//
#include <hip/hip_runtime.h>
#include <math.h>

// SecondOrderChannelAttension on MI355X (gfx950)
// B=32, C=64, H=W=96 -> M=9216, RED=8
//
// Pipeline (3 dispatches):
//   memset   : zero covws/sumws/ctr (532 KB)
//   K1 fused : per-batch Gram (X X^T) via bf16 MFMA 16x16x32 + channel sums;
//              the LAST-ARRIVING block of each batch (agent-scope counter)
//              runs Newton-Schulz sqrt + gate MLP inline. No spin-waits ->
//              deadlock-free regardless of residency.
//   K2 gate_mul: one block per (b,c) row, gate value wave-uniform.

#define BB 32
#define CC 64
#define MM 9216

typedef __attribute__((ext_vector_type(8))) short bf16x8;
typedef __attribute__((ext_vector_type(4))) float f32x4;

__device__ __forceinline__ short f2bf(float f) {
  unsigned u = __builtin_bit_cast(unsigned, f);
  return (short)(unsigned short)((u + 0x8000u) >> 16);  // round-half-up, fine here
}
__device__ __forceinline__ float bf2f(short h) {
  unsigned u = ((unsigned)(unsigned short)h) << 16;
  return __builtin_bit_cast(float, u);
}
// Agent-scope (device-coherent) load: bypasses the per-XCD L2 so the NS block
// sees Gram values accumulated by blocks on other XCDs (G16).
__device__ __forceinline__ float gload(const float* p) {
  return __hip_atomic_load(p, __ATOMIC_RELAXED, __HIP_MEMORY_SCOPE_AGENT);
}

// ---------------- 64x64 NS matmuls (LDS, bf16 MFMA) ----------------
// All NS iterates are symmetric (polynomials in A), so row-major read serves
// as the k-major B fragment.
__device__ __forceinline__ void mm64(short* __restrict__ D, const short* __restrict__ A,
                                     const short* __restrict__ Bm, int tid) {
  int w = tid >> 6, lane = tid & 63, quad = lane >> 4, col = lane & 15;
  f32x4 acc[4];
#pragma unroll
  for (int j = 0; j < 4; j++) acc[j] = (f32x4){0.f, 0.f, 0.f, 0.f};
#pragma unroll
  for (int ks = 0; ks < 2; ks++) {
    int k0 = ks * 32 + quad * 8;
    bf16x8 fa = *(const bf16x8*)(A + (w * 16 + col) * 64 + k0);
#pragma unroll
    for (int j = 0; j < 4; j++) {
      bf16x8 fb = *(const bf16x8*)(Bm + (j * 16 + col) * 64 + k0);
      acc[j] = __builtin_amdgcn_mfma_f32_16x16x32_bf16(fa, fb, acc[j], 0, 0, 0);
    }
  }
#pragma unroll
  for (int j = 0; j < 4; j++)
#pragma unroll
    for (int r = 0; r < 4; r++)
      D[(w * 16 + quad * 4 + r) * 64 + j * 16 + col] = f2bf(acc[j][r]);
}

__device__ __forceinline__ void mmcolsum(const short* __restrict__ A,
                                         const short* __restrict__ Bm,
                                         float* scol, int tid) {
  int w = tid >> 6, lane = tid & 63, quad = lane >> 4, col = lane & 15;
  f32x4 acc[4];
#pragma unroll
  for (int j = 0; j < 4; j++) acc[j] = (f32x4){0.f, 0.f, 0.f, 0.f};
#pragma unroll
  for (int ks = 0; ks < 2; ks++) {
    int k0 = ks * 32 + quad * 8;
    bf16x8 fa = *(const bf16x8*)(A + (w * 16 + col) * 64 + k0);
#pragma unroll
    for (int j = 0; j < 4; j++) {
      bf16x8 fb = *(const bf16x8*)(Bm + (j * 16 + col) * 64 + k0);
      acc[j] = __builtin_amdgcn_mfma_f32_16x16x32_bf16(fa, fb, acc[j], 0, 0, 0);
    }
  }
#pragma unroll
  for (int j = 0; j < 4; j++) {
    float t = (acc[j][0] + acc[j][1]) + (acc[j][2] + acc[j][3]);
    atomicAdd(&scol[j * 16 + col], t);  // sums over all 64 rows across waves/quads
  }
}

// ---------------- K1: fused Gram + (last-arrival) Newton-Schulz ----------------
// grid = BB * 16 blocks, 256 threads (4 waves), 64 KB LDS -> 2 blocks/CU.
// Fragment trick: for Gram, the B-operand fragment (B[k][n] = X[n][k]) has the
// same lane mapping as the A fragment of X rows -> load once, use twice.
#define NCHUNKS 16

template <int NSTEP>
__device__ __forceinline__ void gram_body(const float* __restrict__ xb, int mwave,
                                          int quad, int col,
                                          f32x4 acc[4][4], float csum[4]) {
  const float* base[4];
#pragma unroll
  for (int rb = 0; rb < 4; rb++)
    base[rb] = xb + (size_t)(rb * 16 + col) * MM + mwave + quad * 8;

  float4 cur[4][2];
#pragma unroll
  for (int rb = 0; rb < 4; rb++) {
    cur[rb][0] = *(const float4*)(base[rb]);
    cur[rb][1] = *(const float4*)(base[rb] + 4);
  }
#pragma unroll
  for (int s = 0; s < NSTEP; s++) {
    float4 nxt[4][2];
    if (s + 1 < NSTEP) {
#pragma unroll
      for (int rb = 0; rb < 4; rb++) {
        const float* p = base[rb] + (s + 1) * 32;
        nxt[rb][0] = *(const float4*)(p);
        nxt[rb][1] = *(const float4*)(p + 4);
      }
    }
    bf16x8 frag[4];
#pragma unroll
    for (int rb = 0; rb < 4; rb++) {
      float v0 = cur[rb][0].x, v1 = cur[rb][0].y, v2 = cur[rb][0].z, v3 = cur[rb][0].w;
      float v4 = cur[rb][1].x, v5 = cur[rb][1].y, v6 = cur[rb][1].z, v7 = cur[rb][1].w;
      csum[rb] += ((v0 + v1) + (v2 + v3)) + ((v4 + v5) + (v6 + v7));
      bf16x8 f;
      f[0] = f2bf(v0); f[1] = f2bf(v1); f[2] = f2bf(v2); f[3] = f2bf(v3);
      f[4] = f2bf(v4); f[5] = f2bf(v5); f[6] = f2bf(v6); f[7] = f2bf(v7);
      frag[rb] = f;
    }
#pragma unroll
    for (int i = 0; i < 4; i++)
#pragma unroll
      for (int j = 0; j < 4; j++)
        acc[i][j] = __builtin_amdgcn_mfma_f32_16x16x32_bf16(frag[i], frag[j],
                                                            acc[i][j], 0, 0, 0);
    if (s + 1 < NSTEP) {
#pragma unroll
      for (int rb = 0; rb < 4; rb++) {
        cur[rb][0] = nxt[rb][0];
        cur[rb][1] = nxt[rb][1];
      }
    }
  }
}

__global__ __launch_bounds__(256, 2) void gram_ns_k(
    const float* __restrict__ x, float* __restrict__ covws,
    float* __restrict__ sumws, int* __restrict__ ctr,
    const float* __restrict__ w1, const float* __restrict__ pb1,
    const float* __restrict__ w2, const float* __restrict__ pb2,
    float* __restrict__ gatews) {
  // 64 KB LDS union: gram phase uses all of it as red[4][4096] floats;
  // NS phase carves bf16 buffers + small scratch out of the same bytes.
  __shared__ __align__(16) unsigned char smem[65536];
  float(*red)[4096] = reinterpret_cast<float(*)[4096]>(smem);

  int b = blockIdx.x / NCHUNKS;
  int chunk = blockIdx.x % NCHUNKS;
  int tid = threadIdx.x;
  int w = tid >> 6, lane = tid & 63;
  int quad = lane >> 4, col = lane & 15;
  const float* xb = x + (size_t)b * CC * MM;

  f32x4 acc[4][4];
#pragma unroll
  for (int i = 0; i < 4; i++)
#pragma unroll
    for (int j = 0; j < 4; j++) acc[i][j] = (f32x4){0.f, 0.f, 0.f, 0.f};
  float csum[4] = {0.f, 0.f, 0.f, 0.f};

  // chunks 0-7: 5 steps (640 m per block), chunks 8-15: 4 steps (512 m)
  if (chunk < 8) {
    int mwave = chunk * 640 + w * (5 * 32);
    gram_body<5>(xb, mwave, quad, col, acc, csum);
  } else {
    int mwave = 5120 + (chunk - 8) * 512 + w * (4 * 32);
    gram_body<4>(xb, mwave, quad, col, acc, csum);
  }

  // block-level reduce of the 4 waves' partial Grams, then global atomics
#pragma unroll
  for (int i = 0; i < 4; i++)
#pragma unroll
    for (int j = 0; j < 4; j++)
#pragma unroll
      for (int r = 0; r < 4; r++)
        red[w][(i * 16 + quad * 4 + r) * 64 + j * 16 + col] = acc[i][j][r];
  __syncthreads();
  float* covb = covws + b * 4096;
#pragma unroll
  for (int e = 0; e < 16; e++) {
    int idx = tid + 256 * e;
    float v = (red[0][idx] + red[1][idx]) + (red[2][idx] + red[3][idx]);
    atomicAdd(covb + idx, v);
  }
  // channel sums: lanes (col, quad) of row-block rb all hold channel rb*16+col
#pragma unroll
  for (int rb = 0; rb < 4; rb++) {
    float c0 = csum[rb];
    c0 += __shfl_xor(c0, 16);
    c0 += __shfl_xor(c0, 32);
    if (quad == 0) {
      if (lane < 16) atomicAdd(sumws + b * 64 + rb * 16 + lane, c0);
    }
  }

  // -------- last-arrival election (no waiting; deadlock-free) --------
  __threadfence();   // prior atomics complete at device scope
  __syncthreads();   // all threads of this block fenced; red[] reads done
  int* pold = (int*)(smem + 41600);
  if (tid == 0)
    *pold = __hip_atomic_fetch_add(ctr + b, 1, __ATOMIC_ACQ_REL,
                                   __HIP_MEMORY_SCOPE_AGENT);
  __syncthreads();
  if (*pold != NCHUNKS - 1) return;  // not the last block for this batch

  // -------- Newton-Schulz + gate MLP (runs in the one surviving block) ------
  short* nb0 = (short*)smem;          // 5 x 8 KB bf16 64x64 buffers
  short* nb1 = nb0 + 4096;
  short* nb2 = nb0 + 8192;
  short* nb3 = nb0 + 12288;
  short* nb4 = nb0 + 16384;
  float* mu = (float*)(smem + 40960);
  float* scol = (float*)(smem + 41216);
  float* hbuf = (float*)(smem + 41472);
  float* pnormA = (float*)(smem + 41504);
  const float* gram = covws + b * 4096;

  if (tid < 64) mu[tid] = gload(sumws + b * 64 + tid) * (1.0f / MM);
  __syncthreads();
  if (tid < 64) {
    float d = gload(gram + tid * 65) * (1.0f / MM) - mu[tid] * mu[tid];
#pragma unroll
    for (int off = 32; off >= 1; off >>= 1) d += __shfl_down(d, off);
    if (tid == 0) *pnormA = d;
  }
  __syncthreads();
  float normA = *pnormA;
  float rn = 1.0f / normA;
  // A -> nb0, Z = ZY0 = 1.5I - 0.5A -> nb1
#pragma unroll
  for (int e = 0; e < 16; e++) {
    int idx = tid + 256 * e;
    int r = idx >> 6, c = idx & 63;
    float cv = gload(gram + idx) * (1.0f / MM) - mu[r] * mu[c];
    float a = cv * rn;
    nb0[idx] = f2bf(a);
    nb1[idx] = f2bf((r == c ? 1.5f : 0.0f) - 0.5f * a);
  }
  __syncthreads();
  mm64(nb2, nb0, nb1, tid);  // Y = A @ ZY0
  __syncthreads();
  short *pY = nb2, *pZ = nb1, *s0 = nb3, *s1 = nb4, *s2 = nb0;
  for (int it = 0; it < 3; ++it) {
    // T = 1.5I - 0.5 Z -> s0
#pragma unroll
    for (int e = 0; e < 16; e++) {
      int idx = tid + 256 * e;
      int r = idx >> 6, c = idx & 63;
      float z = bf2f(pZ[idx]);
      s0[idx] = f2bf((r == c ? 1.5f : 0.0f) - 0.5f * z);
    }
    __syncthreads();
    mm64(s1, s0, pY, tid);  // W = T @ Y
    __syncthreads();
    mm64(s2, pY, s1, tid);  // Ynew = Y @ W
    mm64(s0, s1, pZ, tid);  // Znew = W @ Z  (overwrites T; W-matmul already fenced)
    __syncthreads();
    short* oY = pY; short* oZ = pZ; short* oW = s1;
    pY = s2; pZ = s0; s0 = oY; s1 = oZ; s2 = oW;
  }
  mm64(s0, pZ, pY, tid);  // P = Z @ Y
  __syncthreads();
#pragma unroll
  for (int e = 0; e < 16; e++) {  // s0 = 3I - P (in place, own elements only)
    int idx = tid + 256 * e;
    int r = idx >> 6, c = idx & 63;
    float p = bf2f(s0[idx]);
    s0[idx] = f2bf((r == c ? 3.0f : 0.0f) - p);
  }
  if (tid < 64) scol[tid] = 0.0f;
  __syncthreads();
  mmcolsum(pY, s0, scol, tid);  // column sums of R = Y @ (3I - P)
  __syncthreads();
  // s[c] = 0.5*sqrt(normA)/64 * scol[c]; h = relu(s@w1^T + b1); gate = sigmoid(h@w2^T + b2)
  if (tid < 8) {
    float sc = 0.5f * sqrtf(normA) * (1.0f / 64.0f);
    float acc2 = pb1[tid];
    for (int c = 0; c < 64; c++) acc2 += scol[c] * sc * w1[tid * 64 + c];
    hbuf[tid] = fmaxf(acc2, 0.0f);
  }
  __syncthreads();
  if (tid < 64) {
    float acc2 = pb2[tid];
#pragma unroll
    for (int j = 0; j < 8; j++) acc2 += hbuf[j] * w2[tid * 8 + j];
    gatews[b * 64 + tid] = 1.0f / (1.0f + __expf(-acc2));
  }
}

// ---------------- K2: out = x * gate ----------------
// One block per (b,c): gate value is wave-uniform (SGPR), accesses fully
// coalesced. 2048 blocks x 256 threads x 9 float4 = whole tensor.
__global__ __launch_bounds__(256) void gate_mul(const float* __restrict__ x,
                                                const float* __restrict__ gatews,
                                                float* __restrict__ out) {
  int bc = blockIdx.x;
  float g = gatews[bc];
  const float4* xp = (const float4*)(x + (size_t)bc * MM);
  float4* op = (float4*)(out + (size_t)bc * MM);
  int t = threadIdx.x;
#pragma unroll
  for (int it = 0; it < 9; ++it) {
    float4 v = xp[t + it * 256];
    v.x *= g; v.y *= g; v.z *= g; v.w *= g;
    op[t + it * 256] = v;
  }
}

extern "C" void kernel_launch(void* const* d_in, const int* in_sizes, int n_in,
                              void* d_out, int out_size, void* d_ws, size_t ws_size,
                              hipStream_t stream) {
  const float* x = (const float*)d_in[0];
  const float* w1 = (const float*)d_in[1];
  const float* b1 = (const float*)d_in[2];
  const float* w2 = (const float*)d_in[3];
  const float* b2 = (const float*)d_in[4];
  float* out = (float*)d_out;
  float* ws = (float*)d_ws;
  float* covws = ws;                    // 32*4096 fp32
  float* sumws = ws + BB * 4096;        // 32*64 fp32
  int* ctr = (int*)(sumws + BB * 64);   // 32 int
  float* gatews = (float*)(ctr + BB);   // 32*64 fp32 (fully rewritten each run)

  // zero covws + sumws + ctr (contiguous prefix)
  hipMemsetAsync(ws, 0, (size_t)(BB * 4096 + BB * 64 + BB) * sizeof(float), stream);
  gram_ns_k<<<BB * NCHUNKS, 256, 0, stream>>>(x, covws, sumws, ctr, w1, b1, w2,
                                              b2, gatews);
  gate_mul<<<BB * CC, 256, 0, stream>>>(x, gatews, out);
}

// Round 3
// 168.670 us; speedup vs baseline: 1.4168x; 1.4168x over previous
//
#include <hip/hip_runtime.h>
#include <math.h>

// SecondOrderChannelAttension on MI355X (gfx950)
// B=32, C=64, H=W=96 -> M=9216, RED=8
//
// Pipeline (3 dispatches, NO global atomics in the main path):
//   K1 gram_k:   per-(batch,chunk) partial Gram via bf16 MFMA 16x16x32 +
//                partial channel sums, written with plain coalesced stores
//                to a private workspace slice.
//   K2 ns_k:     sum the 16 partials in LDS, cov = Gram/M - mu mu^T,
//                Newton-Schulz sqrt (12 matmuls, bf16 MFMA in LDS,
//                exploiting symmetry of all NS iterates), gate MLP.
//   K3 gate_mul: out = x * gate (one block per (b,c) row, gate wave-uniform).
//
// Fallback: if ws_size < 8.6 MB, use the old atomicAdd accumulation path
// (adds a memset dispatch).

#define BB 32
#define CC 64
#define MM 9216
#define NCHUNKS 16

typedef __attribute__((ext_vector_type(8))) short bf16x8;
typedef __attribute__((ext_vector_type(4))) float f32x4;

__device__ __forceinline__ short f2bf(float f) {
  unsigned u = __builtin_bit_cast(unsigned, f);
  return (short)(unsigned short)((u + 0x8000u) >> 16);  // round-half-up, fine here
}
__device__ __forceinline__ float bf2f(short h) {
  unsigned u = ((unsigned)(unsigned short)h) << 16;
  return __builtin_bit_cast(float, u);
}

// ---------------- K1: Gram + channel sums ----------------
// grid = BB * 16 blocks, 256 threads (4 waves) -> 2 blocks/CU.
// Fragment trick: for Gram, the B-operand fragment (B[k][n] = X[n][k]) has the
// same lane mapping as the A fragment of X rows -> load once, use twice.
template <int NSTEP>
__device__ __forceinline__ void gram_body(const float* __restrict__ xb, int mwave,
                                          int quad, int col,
                                          f32x4 acc[4][4], float csum[4]) {
  const float* base[4];
#pragma unroll
  for (int rb = 0; rb < 4; rb++)
    base[rb] = xb + (size_t)(rb * 16 + col) * MM + mwave + quad * 8;

  float4 cur[4][2];
#pragma unroll
  for (int rb = 0; rb < 4; rb++) {
    cur[rb][0] = *(const float4*)(base[rb]);
    cur[rb][1] = *(const float4*)(base[rb] + 4);
  }
#pragma unroll
  for (int s = 0; s < NSTEP; s++) {
    float4 nxt[4][2];
    if (s + 1 < NSTEP) {
#pragma unroll
      for (int rb = 0; rb < 4; rb++) {
        const float* p = base[rb] + (s + 1) * 32;
        nxt[rb][0] = *(const float4*)(p);
        nxt[rb][1] = *(const float4*)(p + 4);
      }
    }
    bf16x8 frag[4];
#pragma unroll
    for (int rb = 0; rb < 4; rb++) {
      float v0 = cur[rb][0].x, v1 = cur[rb][0].y, v2 = cur[rb][0].z, v3 = cur[rb][0].w;
      float v4 = cur[rb][1].x, v5 = cur[rb][1].y, v6 = cur[rb][1].z, v7 = cur[rb][1].w;
      csum[rb] += ((v0 + v1) + (v2 + v3)) + ((v4 + v5) + (v6 + v7));
      bf16x8 f;
      f[0] = f2bf(v0); f[1] = f2bf(v1); f[2] = f2bf(v2); f[3] = f2bf(v3);
      f[4] = f2bf(v4); f[5] = f2bf(v5); f[6] = f2bf(v6); f[7] = f2bf(v7);
      frag[rb] = f;
    }
#pragma unroll
    for (int i = 0; i < 4; i++)
#pragma unroll
      for (int j = 0; j < 4; j++)
        acc[i][j] = __builtin_amdgcn_mfma_f32_16x16x32_bf16(frag[i], frag[j],
                                                            acc[i][j], 0, 0, 0);
    if (s + 1 < NSTEP) {
#pragma unroll
      for (int rb = 0; rb < 4; rb++) {
        cur[rb][0] = nxt[rb][0];
        cur[rb][1] = nxt[rb][1];
      }
    }
  }
}

// PART=true : plain stores of per-block partials (pg[block][4096], ps[block][64])
// PART=false: atomicAdd accumulation into pg[b][4096], ps[b][64] (legacy)
template <bool PART>
__global__ __launch_bounds__(256, 2) void gram_k(const float* __restrict__ x,
                                                 float* __restrict__ pg,
                                                 float* __restrict__ ps) {
  int b = blockIdx.x / NCHUNKS;
  int chunk = blockIdx.x % NCHUNKS;
  int tid = threadIdx.x;
  int w = tid >> 6, lane = tid & 63;
  int quad = lane >> 4, col = lane & 15;
  const float* xb = x + (size_t)b * CC * MM;

  f32x4 acc[4][4];
#pragma unroll
  for (int i = 0; i < 4; i++)
#pragma unroll
    for (int j = 0; j < 4; j++) acc[i][j] = (f32x4){0.f, 0.f, 0.f, 0.f};
  float csum[4] = {0.f, 0.f, 0.f, 0.f};

  // chunks 0-7: 5 steps (640 m per block), chunks 8-15: 4 steps (512 m)
  if (chunk < 8) {
    int mwave = chunk * 640 + w * (5 * 32);
    gram_body<5>(xb, mwave, quad, col, acc, csum);
  } else {
    int mwave = 5120 + (chunk - 8) * 512 + w * (4 * 32);
    gram_body<4>(xb, mwave, quad, col, acc, csum);
  }

  // block-level reduce of the 4 waves' partial Grams
  __shared__ float red[4][4096];
  __shared__ float cred[4][64];
#pragma unroll
  for (int i = 0; i < 4; i++)
#pragma unroll
    for (int j = 0; j < 4; j++)
#pragma unroll
      for (int r = 0; r < 4; r++)
        red[w][(i * 16 + quad * 4 + r) * 64 + j * 16 + col] = acc[i][j][r];
  // channel sums: after xor-16/32, lanes 0-15 hold the wave's channel sums
#pragma unroll
  for (int rb = 0; rb < 4; rb++) {
    float c0 = csum[rb];
    c0 += __shfl_xor(c0, 16);
    c0 += __shfl_xor(c0, 32);
    if (lane < 16) cred[w][rb * 16 + lane] = c0;
  }
  __syncthreads();

  if (PART) {
    float* covb = pg + (size_t)blockIdx.x * 4096;
#pragma unroll
    for (int e = 0; e < 16; e++) {
      int idx = tid + 256 * e;
      covb[idx] = (red[0][idx] + red[1][idx]) + (red[2][idx] + red[3][idx]);
    }
    if (tid < 64)
      ps[blockIdx.x * 64 + tid] =
          (cred[0][tid] + cred[1][tid]) + (cred[2][tid] + cred[3][tid]);
  } else {
    float* covb = pg + (size_t)b * 4096;
#pragma unroll
    for (int e = 0; e < 16; e++) {
      int idx = tid + 256 * e;
      float v = (red[0][idx] + red[1][idx]) + (red[2][idx] + red[3][idx]);
      atomicAdd(covb + idx, v);
    }
    if (tid < 64) {
      float v = (cred[0][tid] + cred[1][tid]) + (cred[2][tid] + cred[3][tid]);
      atomicAdd(ps + b * 64 + tid, v);
    }
  }
}

// ---------------- K2: Newton-Schulz + gate MLP ----------------
// 64x64 matmul, operands row-major bf16 in LDS. All NS iterates are symmetric
// (polynomials in A), so row-major read serves as the k-major B fragment.
__device__ __forceinline__ void mm64(short* __restrict__ D, const short* __restrict__ A,
                                     const short* __restrict__ Bm, int tid) {
  int w = tid >> 6, lane = tid & 63, quad = lane >> 4, col = lane & 15;
  f32x4 acc[4];
#pragma unroll
  for (int j = 0; j < 4; j++) acc[j] = (f32x4){0.f, 0.f, 0.f, 0.f};
#pragma unroll
  for (int ks = 0; ks < 2; ks++) {
    int k0 = ks * 32 + quad * 8;
    bf16x8 fa = *(const bf16x8*)(A + (w * 16 + col) * 64 + k0);
#pragma unroll
    for (int j = 0; j < 4; j++) {
      bf16x8 fb = *(const bf16x8*)(Bm + (j * 16 + col) * 64 + k0);
      acc[j] = __builtin_amdgcn_mfma_f32_16x16x32_bf16(fa, fb, acc[j], 0, 0, 0);
    }
  }
#pragma unroll
  for (int j = 0; j < 4; j++)
#pragma unroll
    for (int r = 0; r < 4; r++)
      D[(w * 16 + quad * 4 + r) * 64 + j * 16 + col] = f2bf(acc[j][r]);
}

__device__ __forceinline__ void mmcolsum(const short* __restrict__ A,
                                         const short* __restrict__ Bm,
                                         float* scol, int tid) {
  int w = tid >> 6, lane = tid & 63, quad = lane >> 4, col = lane & 15;
  f32x4 acc[4];
#pragma unroll
  for (int j = 0; j < 4; j++) acc[j] = (f32x4){0.f, 0.f, 0.f, 0.f};
#pragma unroll
  for (int ks = 0; ks < 2; ks++) {
    int k0 = ks * 32 + quad * 8;
    bf16x8 fa = *(const bf16x8*)(A + (w * 16 + col) * 64 + k0);
#pragma unroll
    for (int j = 0; j < 4; j++) {
      bf16x8 fb = *(const bf16x8*)(Bm + (j * 16 + col) * 64 + k0);
      acc[j] = __builtin_amdgcn_mfma_f32_16x16x32_bf16(fa, fb, acc[j], 0, 0, 0);
    }
  }
#pragma unroll
  for (int j = 0; j < 4; j++) {
    float t = (acc[j][0] + acc[j][1]) + (acc[j][2] + acc[j][3]);
    atomicAdd(&scol[j * 16 + col], t);  // LDS atomic: sums all 64 rows
  }
}

// PART=true: pg/ps hold per-(b,chunk) partials; sum them here.
// PART=false: pg/ps hold the accumulated gram/sums directly.
template <bool PART>
__global__ __launch_bounds__(256) void ns_k(const float* __restrict__ pg,
                                            const float* __restrict__ ps,
                                            const float* __restrict__ w1,
                                            const float* __restrict__ pb1,
                                            const float* __restrict__ w2,
                                            const float* __restrict__ pb2,
                                            float* __restrict__ gatews) {
  __shared__ __align__(16) short nb0[4096], nb1[4096], nb2[4096], nb3[4096], nb4[4096];
  __shared__ float gsum[4096];
  __shared__ float mu[64];
  __shared__ float scol[64];
  __shared__ float hbuf[8];
  __shared__ float normA_sh;
  int b = blockIdx.x;
  int tid = threadIdx.x;

  // ---- gather gram + mu ----
  if (PART) {
    const float* pgb = pg + (size_t)b * NCHUNKS * 4096;
#pragma unroll
    for (int e = 0; e < 16; e++) {
      int idx = tid + 256 * e;
      float s = 0.f;
#pragma unroll
      for (int c = 0; c < NCHUNKS; c++) s += pgb[c * 4096 + idx];
      gsum[idx] = s;
    }
    if (tid < 64) {
      const float* psb = ps + (size_t)b * NCHUNKS * 64;
      float s = 0.f;
#pragma unroll
      for (int c = 0; c < NCHUNKS; c++) s += psb[c * 64 + tid];
      mu[tid] = s * (1.0f / MM);
    }
  } else {
    const float* gram = pg + (size_t)b * 4096;
#pragma unroll
    for (int e = 0; e < 16; e++) {
      int idx = tid + 256 * e;
      gsum[idx] = gram[idx];
    }
    if (tid < 64) mu[tid] = ps[b * 64 + tid] * (1.0f / MM);
  }
  __syncthreads();

  if (tid < 64) {
    float d = gsum[tid * 65] * (1.0f / MM) - mu[tid] * mu[tid];
#pragma unroll
    for (int off = 32; off >= 1; off >>= 1) d += __shfl_down(d, off);
    if (tid == 0) normA_sh = d;
  }
  __syncthreads();
  float normA = normA_sh;
  float rn = 1.0f / normA;
  // A -> nb0, Z = ZY0 = 1.5I - 0.5A -> nb1
#pragma unroll
  for (int e = 0; e < 16; e++) {
    int idx = tid + 256 * e;
    int r = idx >> 6, c = idx & 63;
    float cv = gsum[idx] * (1.0f / MM) - mu[r] * mu[c];
    float a = cv * rn;
    nb0[idx] = f2bf(a);
    nb1[idx] = f2bf((r == c ? 1.5f : 0.0f) - 0.5f * a);
  }
  __syncthreads();
  mm64(nb2, nb0, nb1, tid);  // Y = A @ ZY0
  __syncthreads();
  short *pY = nb2, *pZ = nb1, *s0 = nb3, *s1 = nb4, *s2 = nb0;
  for (int it = 0; it < 3; ++it) {
    // T = 1.5I - 0.5 Z -> s0
#pragma unroll
    for (int e = 0; e < 16; e++) {
      int idx = tid + 256 * e;
      int r = idx >> 6, c = idx & 63;
      float z = bf2f(pZ[idx]);
      s0[idx] = f2bf((r == c ? 1.5f : 0.0f) - 0.5f * z);
    }
    __syncthreads();
    mm64(s1, s0, pY, tid);  // W = T @ Y
    __syncthreads();
    mm64(s2, pY, s1, tid);  // Ynew = Y @ W
    mm64(s0, s1, pZ, tid);  // Znew = W @ Z  (overwrites T; W-matmul already fenced)
    __syncthreads();
    short* oY = pY; short* oZ = pZ; short* oW = s1;
    pY = s2; pZ = s0; s0 = oY; s1 = oZ; s2 = oW;
  }
  mm64(s0, pZ, pY, tid);  // P = Z @ Y
  __syncthreads();
#pragma unroll
  for (int e = 0; e < 16; e++) {  // s0 = 3I - P (in place, own elements only)
    int idx = tid + 256 * e;
    int r = idx >> 6, c = idx & 63;
    float p = bf2f(s0[idx]);
    s0[idx] = f2bf((r == c ? 3.0f : 0.0f) - p);
  }
  if (tid < 64) scol[tid] = 0.0f;
  __syncthreads();
  mmcolsum(pY, s0, scol, tid);  // column sums of R = Y @ (3I - P)
  __syncthreads();
  // s[c] = 0.5*sqrt(normA)/64 * scol[c]; h = relu(s@w1^T + b1); gate = sigmoid(h@w2^T + b2)
  if (tid < 8) {
    float sc = 0.5f * sqrtf(normA) * (1.0f / 64.0f);
    float acc2 = pb1[tid];
    for (int c = 0; c < 64; c++) acc2 += scol[c] * sc * w1[tid * 64 + c];
    hbuf[tid] = fmaxf(acc2, 0.0f);
  }
  __syncthreads();
  if (tid < 64) {
    float acc2 = pb2[tid];
#pragma unroll
    for (int j = 0; j < 8; j++) acc2 += hbuf[j] * w2[tid * 8 + j];
    gatews[b * 64 + tid] = 1.0f / (1.0f + __expf(-acc2));
  }
}

// ---------------- K3: out = x * gate ----------------
// One block per (b,c): gate value is wave-uniform (SGPR), accesses fully
// coalesced. 2048 blocks x 256 threads x 9 float4 = whole tensor.
__global__ __launch_bounds__(256) void gate_mul(const float* __restrict__ x,
                                                const float* __restrict__ gatews,
                                                float* __restrict__ out) {
  int bc = blockIdx.x;
  float g = gatews[bc];
  const float4* xp = (const float4*)(x + (size_t)bc * MM);
  float4* op = (float4*)(out + (size_t)bc * MM);
  int t = threadIdx.x;
#pragma unroll
  for (int it = 0; it < 9; ++it) {
    float4 v = xp[t + it * 256];
    v.x *= g; v.y *= g; v.z *= g; v.w *= g;
    op[t + it * 256] = v;
  }
}

extern "C" void kernel_launch(void* const* d_in, const int* in_sizes, int n_in,
                              void* d_out, int out_size, void* d_ws, size_t ws_size,
                              hipStream_t stream) {
  const float* x = (const float*)d_in[0];
  const float* w1 = (const float*)d_in[1];
  const float* b1 = (const float*)d_in[2];
  const float* w2 = (const float*)d_in[3];
  const float* b2 = (const float*)d_in[4];
  float* out = (float*)d_out;
  float* ws = (float*)d_ws;

  const size_t NPG = (size_t)BB * NCHUNKS * 4096;  // 2M floats = 8 MB
  const size_t NPS = (size_t)BB * NCHUNKS * 64;    // 32K floats = 128 KB
  const size_t needP = (NPG + NPS + BB * CC) * sizeof(float);

  if (ws_size >= needP) {
    // ---- main path: no global atomics, no memset ----
    float* pg = ws;
    float* psum = ws + NPG;
    float* gatews = psum + NPS;
    gram_k<true><<<BB * NCHUNKS, 256, 0, stream>>>(x, pg, psum);
    ns_k<true><<<BB, 256, 0, stream>>>(pg, psum, w1, b1, w2, b2, gatews);
    gate_mul<<<BB * CC, 256, 0, stream>>>(x, gatews, out);
  } else {
    // ---- fallback: legacy atomic accumulation ----
    float* covws = ws;                   // 32*4096 fp32
    float* sumws = ws + BB * 4096;       // 32*64 fp32
    float* gatews = sumws + BB * 64;     // 32*64 fp32
    hipMemsetAsync(ws, 0, (size_t)(BB * 4096 + BB * 64) * sizeof(float), stream);
    gram_k<false><<<BB * NCHUNKS, 256, 0, stream>>>(x, covws, sumws);
    ns_k<false><<<BB, 256, 0, stream>>>(covws, sumws, w1, b1, w2, b2, gatews);
    gate_mul<<<BB * CC, 256, 0, stream>>>(x, gatews, out);
  }
}